// Round 5
// baseline (445.621 us; speedup 1.0000x reference)
//
#include <hip/hip_runtime.h>
#include <hip/hip_bf16.h>

typedef __hip_bfloat16 bf16;
typedef float f32x4 __attribute__((ext_vector_type(4)));
typedef short s16x8 __attribute__((ext_vector_type(8)));

#define B_   16
#define CIN  256
#define CQK  32
#define CV   128
#define VDIM 64
#define TDIM 64
#define P    (VDIM * TDIM)   // 4096

static __device__ __forceinline__ ushort f2bf(float f) {
    bf16 h = __float2bfloat16(f);
    return *(ushort*)&h;
}
static __device__ __forceinline__ float bf2f(ushort u) {
    bf16 h = *(bf16*)&u;
    return __bfloat162float(h);
}

// ---------------------------------------------------------------------------
// repack_w:
//  wq,wk [32][256][3][3] f32 -> wqh/wql [9][64][256] bf16 hi/lo (oc<32 q else k)
//  wv [128][256][3][3] -> wvT [9][128][256] bf16
//  wo [256][128][3][3] -> woT [9][256][128] bf16
// ---------------------------------------------------------------------------
__global__ __launch_bounds__(256) void repack_w(
    const float* __restrict__ wq, const float* __restrict__ wk,
    const float* __restrict__ wv, const float* __restrict__ wo,
    ushort* __restrict__ wvT, ushort* __restrict__ woT,
    ushort* __restrict__ wqh, ushort* __restrict__ wql)
{
    int i = blockIdx.x * 256 + threadIdx.x;
    const int NQK = 9 * 64 * 256;      // 147456
    const int NV  = 9 * 128 * 256;     // 294912
    if (i < NQK) {
        int tap = i / (64 * 256);
        int r   = i % (64 * 256);
        int oc  = r >> 8;
        int ci  = r & 255;
        const float* src = (oc < 32) ? wq : wk;
        float f = src[(size_t)(oc & 31) * 2304 + ci * 9 + tap];
        ushort h = f2bf(f);
        wqh[i] = h;
        wql[i] = f2bf(f - bf2f(h));
    } else if (i < NQK + NV) {
        i -= NQK;
        int tap = i / (128 * 256);
        int r   = i % (128 * 256);
        int oc  = r >> 8;
        int ci  = r & 255;
        wvT[i] = f2bf(wv[(size_t)oc * 2304 + ci * 9 + tap]);
    } else {
        i -= NQK + NV;
        int tap = i / (256 * 128);
        int r   = i % (256 * 128);
        int oc  = r >> 7;
        int ci  = r & 127;
        woT[i] = f2bf(wo[(size_t)oc * 1152 + ci * 9 + tap]);
    }
}

// ---------------------------------------------------------------------------
// repack_x2: x [B][256][64y][64t] f32 -> xh,xl [B][64t][64y][256ci] bf16
// (hi = bf16(x), lo = bf16(x - hi)) in ONE pass over x.
// ---------------------------------------------------------------------------
__global__ __launch_bounds__(256) void repack_x2(
    const float* __restrict__ x, ushort* __restrict__ xhd, ushort* __restrict__ xld)
{
    const int b = blockIdx.x >> 6;
    const int y = blockIdx.x & 63;
    __shared__ ushort th[64][257];
    __shared__ ushort tl_[64][257];
    const int t  = threadIdx.x & 63;
    const int cq = threadIdx.x >> 6;
    const float* xb = x + (((size_t)b * CIN) * VDIM + y) * TDIM;
    for (int ci = cq; ci < 256; ci += 4) {
        float f = xb[(size_t)ci * P + t];
        ushort h = f2bf(f);
        th[t][ci]  = h;
        tl_[t][ci] = f2bf(f - bf2f(h));
    }
    __syncthreads();
    const int ci4 = (threadIdx.x & 63) * 4;
    const int tr0 = threadIdx.x >> 6;
    for (int tr = tr0; tr < 64; tr += 4) {
        ushort4 uh, ul;
        uh.x = th[tr][ci4];     uh.y = th[tr][ci4 + 1];
        uh.z = th[tr][ci4 + 2]; uh.w = th[tr][ci4 + 3];
        ul.x = tl_[tr][ci4];     ul.y = tl_[tr][ci4 + 1];
        ul.z = tl_[tr][ci4 + 2]; ul.w = tl_[tr][ci4 + 3];
        const size_t o = ((((size_t)b * 64 + tr) * 64 + y) * 256 + ci4);
        *(ushort4*)(xhd + o) = uh;
        *(ushort4*)(xld + o) = ul;
    }
}

// Stage one [3 dx][66 yl][128 ci] bf16 halo tile into swizzled LDS.
#define STAGE_TILE(SRC, CI0)                                                      \
    for (int idx = tid; idx < 198 * 16; idx += 256) {                             \
        const int row = idx >> 4, ch = idx & 15;                                  \
        const int dxs = row / 66, yl = row % 66;                                  \
        const int tp = t0 + dxs - 1, yp = yl - 1;                                 \
        int4 val = {0, 0, 0, 0};                                                  \
        if ((unsigned)tp < 64u && (unsigned)yp < 64u)                             \
            val = *(const int4*)((SRC) + ((((size_t)b * 64 + tp) * 64 + yp) * 256 \
                                          + (CI0) + ch * 8));                     \
        const int byte_off = row * 256 + ((ch * 16) ^ ((row & 7) << 4));          \
        *(int4*)((char*)btile + byte_off) = val;                                  \
    }

// Read the 4 B-fragments for one tap (dy,dxp) at k-step kk.
#define READ_BFR(BFR, DY, DXP, KK)                                                \
    {                                                                             \
        _Pragma("unroll")                                                         \
        for (int nf = 0; nf < 4; ++nf) {                                          \
            const int yl = nf * 16 + (lane & 15) + (DY);                          \
            const int row = (DXP) * 66 + yl;                                      \
            const int bir = (KK) * 64 + (lane >> 4) * 16;                         \
            BFR[nf] = *(const s16x8*)((const char*)btile + row * 256 +            \
                                      (bir ^ ((row & 7) << 4)));                  \
        }                                                                         \
    }

// ---------------------------------------------------------------------------
// qkvattn: fused q/k/v 3x3 conv (MFMA implicit GEMM) + attention per (b,t0).
//  v: 128 oc bf16-weight 1-pass; q,k: 32+32 oc split-bf16 3-pass (fp32-accurate).
//  Weight fragments software-pipelined at DEPTH 1 (4 frags live max -> no
//  spills under the 128-VGPR cap; round-4's depth-9 batch spilled 64 regs).
// ---------------------------------------------------------------------------
__global__ __launch_bounds__(256, 2) void qkvattn(
    const ushort* __restrict__ xh, const ushort* __restrict__ xl,
    const ushort* __restrict__ wvT,
    const ushort* __restrict__ wqh, const ushort* __restrict__ wql,
    float* __restrict__ attn_out, ushort* __restrict__ av)
{
    // XCD-bijective swizzle (1024 blocks, 8 XCDs, 128/XCD)
    const int bid  = ((blockIdx.x & 7) << 7) | (blockIdx.x >> 3);
    const int b    = bid >> 6;
    const int t0   = bid & 63;
    const int tid  = threadIdx.x;
    const int lane = tid & 63;
    const int w    = tid >> 6;

    __shared__ __align__(16) char smem[50688];
    ushort* btile = (ushort*)smem;

    f32x4 accv[2][4];
    f32x4 accq[4];
#pragma unroll
    for (int m = 0; m < 2; ++m)
#pragma unroll
        for (int nf = 0; nf < 4; ++nf) accv[m][nf] = (f32x4){0.f, 0.f, 0.f, 0.f};
#pragma unroll
    for (int nf = 0; nf < 4; ++nf) accq[nf] = (f32x4){0.f, 0.f, 0.f, 0.f};

    const int ocv  = w * 32 + (lane & 15);        // v channel base (m adds 16)
    const int ocqk = w * 16 + (lane & 15);        // combined q|k channel
    const int ko8  = (lane >> 4) * 8;

    for (int chunk = 0; chunk < 2; ++chunk) {
        const int ci0 = chunk * 128;

        __syncthreads();
        STAGE_TILE(xh, ci0)
        __syncthreads();

        // ---- v pass (wv · x_hi), depth-1 weight prefetch ----
        for (int kk = 0; kk < 4; ++kk) {
#define WVO(TAP, M) (const s16x8*)(wvT + (size_t)((TAP) * 128 + ocv + (M) * 16) * 256 + ci0 + kk * 32 + ko8)
            s16x8 wa = *WVO(0, 0), wb = *WVO(0, 1);
#pragma unroll
            for (int tap = 0; tap < 9; ++tap) {
                s16x8 na, nb;
                if (tap < 8) { na = *WVO(tap + 1, 0); nb = *WVO(tap + 1, 1); }
                s16x8 bfr[4];
                READ_BFR(bfr, tap / 3, tap % 3, kk)
#pragma unroll
                for (int nf = 0; nf < 4; ++nf)
                    accv[0][nf] = __builtin_amdgcn_mfma_f32_16x16x32_bf16(wa, bfr[nf], accv[0][nf], 0, 0, 0);
#pragma unroll
                for (int nf = 0; nf < 4; ++nf)
                    accv[1][nf] = __builtin_amdgcn_mfma_f32_16x16x32_bf16(wb, bfr[nf], accv[1][nf], 0, 0, 0);
                if (tap < 8) { wa = na; wb = nb; }
            }
#undef WVO
        }

        // ---- qk hi pass (w_hi·x_hi + w_lo·x_hi), depth-1 prefetch ----
        for (int kk = 0; kk < 4; ++kk) {
#define WQO(ARR, TAP) (const s16x8*)((ARR) + (size_t)((TAP) * 64 + ocqk) * 256 + ci0 + kk * 32 + ko8)
            s16x8 wa = *WQO(wqh, 0), wb = *WQO(wql, 0);
#pragma unroll
            for (int tap = 0; tap < 9; ++tap) {
                s16x8 na, nb;
                if (tap < 8) { na = *WQO(wqh, tap + 1); nb = *WQO(wql, tap + 1); }
                s16x8 bfr[4];
                READ_BFR(bfr, tap / 3, tap % 3, kk)
#pragma unroll
                for (int nf = 0; nf < 4; ++nf)
                    accq[nf] = __builtin_amdgcn_mfma_f32_16x16x32_bf16(wa, bfr[nf], accq[nf], 0, 0, 0);
#pragma unroll
                for (int nf = 0; nf < 4; ++nf)
                    accq[nf] = __builtin_amdgcn_mfma_f32_16x16x32_bf16(wb, bfr[nf], accq[nf], 0, 0, 0);
                if (tap < 8) { wa = na; wb = nb; }
            }
        }

        __syncthreads();
        STAGE_TILE(xl, ci0)
        __syncthreads();

        // ---- qk lo pass (w_hi·x_lo), depth-1 prefetch ----
        for (int kk = 0; kk < 4; ++kk) {
            s16x8 wa = *WQO(wqh, 0);
#pragma unroll
            for (int tap = 0; tap < 9; ++tap) {
                s16x8 na;
                if (tap < 8) na = *WQO(wqh, tap + 1);
                s16x8 bfr[4];
                READ_BFR(bfr, tap / 3, tap % 3, kk)
#pragma unroll
                for (int nf = 0; nf < 4; ++nf)
                    accq[nf] = __builtin_amdgcn_mfma_f32_16x16x32_bf16(wa, bfr[nf], accq[nf], 0, 0, 0);
                if (tap < 8) wa = na;
            }
#undef WQO
        }
    }
    __syncthreads();   // btile dead; repurpose LDS for attention

    float (*qs)[33]   = (float(*)[33])smem;                //     0 ..  8448
    float (*ks)[33]   = (float(*)[33])(smem + 8448);       //  8448 .. 16896
    float (*S)[65]    = (float(*)[65])(smem + 16896);      // 16896 .. 33536
    ushort (*vs)[132] = (ushort(*)[132])(smem + 33536);    // 33536 .. 50432

    // q,k accumulators -> qs/ks (no global round-trip)
    {
        float (*dst)[33] = (w < 2) ? qs : ks;
        const int c0 = (w & 1) * 16 + (lane >> 4) * 4;
#pragma unroll
        for (int nf = 0; nf < 4; ++nf) {
            const int yy = nf * 16 + (lane & 15);
#pragma unroll
            for (int r = 0; r < 4; ++r) dst[yy][c0 + r] = accq[nf][r];
        }
    }
    // v accumulators -> vs (bf16)
#pragma unroll
    for (int m = 0; m < 2; ++m)
#pragma unroll
        for (int nf = 0; nf < 4; ++nf) {
            const int yy = nf * 16 + (lane & 15);
            const int c0 = w * 32 + m * 16 + (lane >> 4) * 4;
            ushort4 u;
            u.x = f2bf(accv[m][nf][0]); u.y = f2bf(accv[m][nf][1]);
            u.z = f2bf(accv[m][nf][2]); u.w = f2bf(accv[m][nf][3]);
            *(ushort4*)&vs[yy][c0] = u;
        }
    __syncthreads();

    // S = q k^T
    for (int idx = tid; idx < 4096; idx += 256) {
        const int i = idx >> 6, j = idx & 63;
        float s = 0.f;
#pragma unroll
        for (int c = 0; c < 32; ++c) s += qs[i][c] * ks[j][c];
        S[i][j] = s;
    }
    __syncthreads();

    // softmax rows: 4 lanes/row
    {
        const int row = tid >> 2, sub = tid & 3;
        float m = -INFINITY;
#pragma unroll
        for (int jj = 0; jj < 16; ++jj) m = fmaxf(m, S[row][sub * 16 + jj]);
        m = fmaxf(m, __shfl_xor(m, 1));
        m = fmaxf(m, __shfl_xor(m, 2));
        float e[16], sum = 0.f;
#pragma unroll
        for (int jj = 0; jj < 16; ++jj) {
            e[jj] = expf(S[row][sub * 16 + jj] - m);
            sum += e[jj];
        }
        sum += __shfl_xor(sum, 1);
        sum += __shfl_xor(sum, 2);
        const float inv = 1.f / sum;
#pragma unroll
        for (int jj = 0; jj < 16; ++jj) S[row][sub * 16 + jj] = e[jj] * inv;
    }
    __syncthreads();

    // attn write (coalesced)
    float* ao = attn_out + (size_t)bid * 4096;
    for (int idx = tid; idx < 4096; idx += 256)
        ao[idx] = S[idx >> 6][idx & 63];

    // AV
    {
        const int i = tid & 63, quad = tid >> 6;
        float fa[32];
#pragma unroll
        for (int cc = 0; cc < 32; ++cc) fa[cc] = 0.f;
        for (int j = 0; j < 64; ++j) {
            const float s = S[i][j];
#pragma unroll
            for (int cc = 0; cc < 32; ++cc)
                fa[cc] += s * bf2f(vs[j][quad * 32 + cc]);
        }
        ushort* avb = av + (size_t)bid * 8192 + (size_t)i * 128 + quad * 32;
#pragma unroll
        for (int cc = 0; cc < 32; ++cc) avb[cc] = f2bf(fa[cc]);
    }
}

// ---------------------------------------------------------------------------
// out_conv_mfma: block=(b,y,mt): M=128 oc, N=64 t, K=128ci*9tap.
// Depth-1 weight prefetch. out fp32 + residual.
// ---------------------------------------------------------------------------
__global__ __launch_bounds__(256, 2) void out_conv_mfma(
    const float* __restrict__ x,
    const ushort* __restrict__ av,
    const ushort* __restrict__ woT,
    const float* __restrict__ sigma,
    float* __restrict__ out)
{
    // XCD-bijective swizzle (2048 blocks, 256/XCD)
    const int bid  = ((blockIdx.x & 7) << 8) | (blockIdx.x >> 3);
    const int mt   = bid & 1;
    const int y    = (bid >> 1) & 63;
    const int b    = bid >> 7;
    const int tid  = threadIdx.x;
    const int lane = tid & 63;
    const int w    = tid >> 6;

    __shared__ ushort btile[3 * 66 * 128];

    f32x4 acc[2][4];
#pragma unroll
    for (int m = 0; m < 2; ++m)
#pragma unroll
        for (int nf = 0; nf < 4; ++nf) acc[m][nf] = (f32x4){0.f, 0.f, 0.f, 0.f};

    for (int idx = tid; idx < 198 * 16; idx += 256) {
        const int row = idx >> 4, ch = idx & 15;
        const int dy = row / 66, tl = row % 66;
        const int yp = y + dy - 1, tp = tl - 1;
        int4 val = {0, 0, 0, 0};
        if ((unsigned)yp < 64u && (unsigned)tp < 64u)
            val = *(const int4*)(av + ((((size_t)b * 64 + tp) * 64 + yp) * 128 + ch * 8));
        const int byte_off = row * 256 + ((ch * 16) ^ ((row & 7) << 4));
        *(int4*)((char*)btile + byte_off) = val;
    }
    __syncthreads();

    const int oc  = mt * 128 + w * 32 + (lane & 15);
    const int ko8 = (lane >> 4) * 8;
    for (int kk = 0; kk < 4; ++kk) {
#define WOO(TAP, M) (const s16x8*)(woT + (size_t)((TAP) * 256 + oc + (M) * 16) * 128 + kk * 32 + ko8)
        s16x8 wa = *WOO(0, 0), wb = *WOO(0, 1);
#pragma unroll
        for (int tap = 0; tap < 9; ++tap) {
            s16x8 na, nb;
            if (tap < 8) { na = *WOO(tap + 1, 0); nb = *WOO(tap + 1, 1); }
            const int dy = tap / 3, dxp = tap % 3;
            s16x8 bfr[4];
#pragma unroll
            for (int nf = 0; nf < 4; ++nf) {
                const int tl = nf * 16 + (lane & 15) + dxp;
                const int row = dy * 66 + tl;
                const int bir = kk * 64 + (lane >> 4) * 16;
                bfr[nf] = *(const s16x8*)((const char*)btile + row * 256 + (bir ^ ((row & 7) << 4)));
            }
#pragma unroll
            for (int nf = 0; nf < 4; ++nf)
                acc[0][nf] = __builtin_amdgcn_mfma_f32_16x16x32_bf16(wa, bfr[nf], acc[0][nf], 0, 0, 0);
#pragma unroll
            for (int nf = 0; nf < 4; ++nf)
                acc[1][nf] = __builtin_amdgcn_mfma_f32_16x16x32_bf16(wb, bfr[nf], acc[1][nf], 0, 0, 0);
            if (tap < 8) { wa = na; wb = nb; }
        }
#undef WOO
    }

    const float s = sigma[0];
#pragma unroll
    for (int m = 0; m < 2; ++m)
#pragma unroll
        for (int nf = 0; nf < 4; ++nf)
#pragma unroll
            for (int r = 0; r < 4; ++r) {
                const int occ = mt * 128 + w * 32 + m * 16 + (lane >> 4) * 4 + r;
                const int t   = nf * 16 + (lane & 15);
                const size_t a = (((size_t)b * 256 + occ) * 64 + y) * 64 + t;
                out[a] = x[a] + s * acc[m][nf][r];
            }
}

// ---------------------------------------------------------------------------
extern "C" void kernel_launch(void* const* d_in, const int* in_sizes, int n_in,
                              void* d_out, int out_size, void* d_ws, size_t ws_size,
                              hipStream_t stream)
{
    const float* x     = (const float*)d_in[0];
    const float* wq    = (const float*)d_in[1];
    const float* wk    = (const float*)d_in[2];
    const float* wv    = (const float*)d_in[3];
    const float* wo    = (const float*)d_in[4];
    const float* sigma = (const float*)d_in[5];

    float* out      = (float*)d_out;                 // [16,256,64,64]
    float* attn_out = out + (size_t)16777216;        // [1024,64,64]

    // x hi/lo bf16 alias the out-image region (dead until out_conv_mfma):
    ushort* xh = (ushort*)d_out;                     // 16,777,216 bf16 = 32 MiB
    ushort* xl = xh + (size_t)16777216;              // 32 MiB (ends at attn_out)

    // d_ws: av | weights  (~17.8 MiB)
    ushort* av  = (ushort*)d_ws;                     // 8,388,608 bf16
    ushort* wvT = av + 8388608;                      // 294,912
    ushort* woT = wvT + 294912;                      // 294,912
    ushort* wqh = woT + 294912;                      // 147,456
    ushort* wql = wqh + 147456;                      // 147,456

    repack_w<<<2880, 256, 0, stream>>>(wq, wk, wv, wo, wvT, woT, wqh, wql);
    repack_x2<<<B_ * VDIM, 256, 0, stream>>>(x, xh, xl);
    qkvattn<<<B_ * TDIM, 256, 0, stream>>>(xh, xl, wvT, wqh, wql, attn_out, av);
    out_conv_mfma<<<B_ * VDIM * 2, 256, 0, stream>>>(x, av, woT, sigma, out);
}